// Round 1
// baseline (173.144 us; speedup 1.0000x reference)
//
#include <hip/hip_runtime.h>
#include <hip/hip_bf16.h>

typedef short bf16x8 __attribute__((ext_vector_type(8)));
typedef float f32x4  __attribute__((ext_vector_type(4)));

#define T_AUDIO 262144
#define PAD 384
#define NFRAMES 1024
#define NFFT 1024
#define CUTOFF 513
#define MPAD 1152      // padded interleaved freq rows (>= 1026, mult of 128)
#define CPAD 576       // MPAD/2 : padded mag rows / mel K
#define NMELS 80

__device__ __forceinline__ unsigned short f2bf(float f){
  union { float f; unsigned u; } v; v.f = f;
  return (unsigned short)((v.u + 0x7FFFu + ((v.u >> 16) & 1u)) >> 16);
}

__device__ __forceinline__ void gload_lds16(const void* g, void* l){
  __builtin_amdgcn_global_load_lds(
      (const __attribute__((address_space(1))) unsigned int*)g,
      (__attribute__((address_space(3))) unsigned int*)l, 16, 0, 0);
}

// ---------------- prep: frames [32][1024][1024] bf16, reflect-padded ----------------
__global__ void k_frames(const float* __restrict__ audio, unsigned short* __restrict__ frames){
  int gid = blockIdx.x * 256 + threadIdx.x;       // 32*1024*128 units of 8 elems
  int b   = gid >> 17;
  int rem = gid & 131071;
  int t   = rem >> 7;
  int k0  = (rem & 127) << 3;
  int s0  = t * 256 + k0 - PAD;
  const float* ap = audio + (long)b * T_AUDIO;
  float v[8];
  if (s0 >= 0 && s0 + 7 < T_AUDIO){
    f32x4 a0 = *(const f32x4*)(ap + s0);
    f32x4 a1 = *(const f32x4*)(ap + s0 + 4);
    v[0]=a0[0]; v[1]=a0[1]; v[2]=a0[2]; v[3]=a0[3];
    v[4]=a1[0]; v[5]=a1[1]; v[6]=a1[2]; v[7]=a1[3];
  } else {
    #pragma unroll
    for (int e = 0; e < 8; ++e){
      int s = s0 + e;
      if (s < 0) s = -s;
      if (s >= T_AUDIO) s = 2*(T_AUDIO-1) - s;
      v[e] = ap[s];
    }
  }
  bf16x8 o;
  #pragma unroll
  for (int e = 0; e < 8; ++e) o[e] = (short)f2bf(v[e]);
  *(bf16x8*)(frames + ((long)b << 20) + t * 1024 + k0) = o;
}

// ---------------- prep: interleaved basis [1152][1024] bf16 ----------------
// row m: part = m&1, c = m>>1  -> src row c + 513*part ; rows >= 1026 are zero
__global__ void k_basis(const float* __restrict__ basis, unsigned short* __restrict__ bi){
  int gid = blockIdx.x * 256 + threadIdx.x;       // 1152*128 units of 8
  int m  = gid >> 7;
  int k0 = (gid & 127) << 3;
  bf16x8 o = (bf16x8)0;
  if (m < 2*CUTOFF){
    int src = (m >> 1) + CUTOFF * (m & 1);
    f32x4 a0 = *(const f32x4*)(basis + src * 1024 + k0);
    f32x4 a1 = *(const f32x4*)(basis + src * 1024 + k0 + 4);
    o[0]=(short)f2bf(a0[0]); o[1]=(short)f2bf(a0[1]); o[2]=(short)f2bf(a0[2]); o[3]=(short)f2bf(a0[3]);
    o[4]=(short)f2bf(a1[0]); o[5]=(short)f2bf(a1[1]); o[6]=(short)f2bf(a1[2]); o[7]=(short)f2bf(a1[3]);
  }
  *(bf16x8*)(bi + m * 1024 + k0) = o;
}

// ---------------- prep: mel weights [80][576] bf16, zero-padded cols ----------------
__global__ void k_w(const float* __restrict__ w, unsigned short* __restrict__ wb){
  int gid = blockIdx.x * 256 + threadIdx.x;       // 80*576 = 46080
  if (gid >= NMELS * CPAD) return;
  int m = gid / CPAD, c = gid % CPAD;
  float v = (c < CUTOFF) ? w[m * CUTOFF + c] : 0.f;
  wb[gid] = f2bf(v);
}

// ---------------- STFT GEMM + |.| epilogue -> magT [b][t][576] bf16 ----------------
// D[m'][t] = sum_k basisI[m'][k] * frames[t][k];  mag[c=m'/2][t] = sqrt(re^2+im^2)
__launch_bounds__(256)
__global__ void k_stft(const unsigned short* __restrict__ bi,
                       const unsigned short* __restrict__ frames,
                       unsigned short* __restrict__ magT){
  __shared__ unsigned short As[128 * 64];
  __shared__ unsigned short Bs[128 * 64];
  int tid  = threadIdx.x;
  int bx   = blockIdx.x;
  int bm   = bx % 9;
  int bt   = (bx / 9) & 7;
  int b    = bx / 72;
  int m0   = bm * 128, t0 = bt * 128;
  int lane = tid & 63, wid = tid >> 6;
  int wm   = wid >> 1, wn = wid & 1;

  f32x4 acc[4][4] = {};
  const char* Ab = (const char*)(bi + m0 * 1024);
  const char* Bb = (const char*)(frames + ((long)b << 20) + (long)t0 * 1024);

  for (int kt = 0; kt < 16; ++kt){
    int k0b = kt * 128;                 // k0 * 2 bytes
    #pragma unroll
    for (int q = 0; q < 4; ++q){
      int o    = (q * 256 + tid) * 16;  // byte offset in 16KB tile
      int row  = o >> 7;
      int colb = o & 127;
      gload_lds16(Ab + row * 2048 + k0b + colb, (char*)As + q * 4096 + wid * 1024);
      gload_lds16(Bb + row * 2048 + k0b + colb, (char*)Bs + q * 4096 + wid * 1024);
    }
    __syncthreads();
    #pragma unroll
    for (int s = 0; s < 2; ++s){
      bf16x8 af[4], bfr[4];
      int kb = s * 64 + ((lane >> 4) << 4);
      #pragma unroll
      for (int i = 0; i < 4; ++i)
        af[i] = *(const bf16x8*)((const char*)As + (wm*64 + i*16 + (lane & 15)) * 128 + kb);
      #pragma unroll
      for (int j = 0; j < 4; ++j)
        bfr[j] = *(const bf16x8*)((const char*)Bs + (wn*64 + j*16 + (lane & 15)) * 128 + kb);
      #pragma unroll
      for (int i = 0; i < 4; ++i)
        #pragma unroll
        for (int j = 0; j < 4; ++j)
          acc[i][j] = __builtin_amdgcn_mfma_f32_16x16x32_bf16(af[i], bfr[j], acc[i][j], 0, 0, 0);
    }
    __syncthreads();
  }
  // epilogue: rows (4q,4q+1)=pair c0, (4q+2,4q+3)=pair c0+1 ; write two bf16 as u32
  #pragma unroll
  for (int i = 0; i < 4; ++i){
    int mrow0 = m0 + wm*64 + i*16 + ((lane >> 4) << 2);   // multiple of 4
    int c0    = mrow0 >> 1;                               // even
    #pragma unroll
    for (int j = 0; j < 4; ++j){
      int t = t0 + wn*64 + j*16 + (lane & 15);
      f32x4 d = acc[i][j];
      float m1 = sqrtf(d[0]*d[0] + d[1]*d[1]);
      float m2 = sqrtf(d[2]*d[2] + d[3]*d[3]);
      unsigned pack = (unsigned)f2bf(m1) | ((unsigned)f2bf(m2) << 16);
      *(unsigned*)(magT + ((long)b * 1024 + t) * CPAD + c0) = pack;
    }
  }
}

// ---------------- mel GEMM + log(clip) epilogue -> out [32][80][1024] f32 ----------------
// out[m][t] = log(max(sum_c W[m][c] * magT[t][c], 1e-5))
__launch_bounds__(256)
__global__ void k_mel(const unsigned short* __restrict__ wb,
                      const unsigned short* __restrict__ magT,
                      float* __restrict__ out){
  __shared__ unsigned short Ws[80 * 32];    // 5120 B
  __shared__ unsigned short Ms[128 * 32];   // 8192 B
  int tid  = threadIdx.x, lane = tid & 63, wid = tid >> 6;
  int bx   = blockIdx.x;
  int bt   = bx & 7, b = bx >> 3;
  int t0   = bt * 128;
  f32x4 acc[5][2] = {};
  const char* Mb = (const char*)(magT + ((long)b * 1024 + t0) * CPAD);
  const char* Wb = (const char*)wb;

  for (int kt = 0; kt < 18; ++kt){
    int k0b = kt * 64;                      // bytes
    {
      int o = tid * 16;                     // first 4096 B of W tile
      gload_lds16(Wb + (o >> 6) * 1152 + k0b + (o & 63), (char*)Ws + wid * 1024);
      if (wid == 0){                        // tail rows 64..79 (1024 B)
        int o2 = 4096 + lane * 16;
        gload_lds16(Wb + (o2 >> 6) * 1152 + k0b + (o2 & 63), (char*)Ws + 4096);
      }
    }
    #pragma unroll
    for (int q = 0; q < 2; ++q){
      int o = (q * 256 + tid) * 16;
      gload_lds16(Mb + (long)(o >> 6) * 1152 + k0b + (o & 63), (char*)Ms + q * 4096 + wid * 1024);
    }
    __syncthreads();
    bf16x8 af[5], bfr[2];
    int kb = (lane >> 4) << 4;
    #pragma unroll
    for (int i = 0; i < 5; ++i)
      af[i] = *(const bf16x8*)((const char*)Ws + (i*16 + (lane & 15)) * 64 + kb);
    #pragma unroll
    for (int j = 0; j < 2; ++j)
      bfr[j] = *(const bf16x8*)((const char*)Ms + (wid*32 + j*16 + (lane & 15)) * 64 + kb);
    #pragma unroll
    for (int i = 0; i < 5; ++i)
      #pragma unroll
      for (int j = 0; j < 2; ++j)
        acc[i][j] = __builtin_amdgcn_mfma_f32_16x16x32_bf16(af[i], bfr[j], acc[i][j], 0, 0, 0);
    __syncthreads();
  }
  #pragma unroll
  for (int i = 0; i < 5; ++i)
    #pragma unroll
    for (int j = 0; j < 2; ++j){
      int m = i*16 + ((lane >> 4) << 2);
      int t = t0 + wid*32 + j*16 + (lane & 15);
      #pragma unroll
      for (int r = 0; r < 4; ++r){
        float v = acc[i][j][r];
        out[((long)b * NMELS + (m + r)) * 1024 + t] = logf(fmaxf(v, 1e-5f));
      }
    }
}

__global__ void k_sentinel(float* out, int n){
  int i = blockIdx.x * 256 + threadIdx.x;
  if (i < n) out[i] = 12345.0f;
}

extern "C" void kernel_launch(void* const* d_in, const int* in_sizes, int n_in,
                              void* d_out, int out_size, void* d_ws, size_t ws_size,
                              hipStream_t stream){
  const float* audio = (const float*)d_in[0];
  const float* basis = (const float*)d_in[1];
  const float* melw  = (const float*)d_in[2];
  float* out = (float*)d_out;

  size_t off_frames = 0;
  size_t off_bi     = off_frames + (size_t)32 * 1024 * 1024 * 2;        // 67,108,864
  size_t off_wb     = off_bi     + (size_t)MPAD * 1024 * 2;             // +2,359,296
  size_t off_mag    = off_wb     + (size_t)NMELS * CPAD * 2;            // +92,160
  size_t total      = off_mag    + (size_t)32 * 1024 * CPAD * 2;        // +37,748,736 = 107,309,056

  if (ws_size < total){
    k_sentinel<<<(out_size + 255) / 256, 256, 0, stream>>>(out, out_size);
    return;
  }
  char* ws = (char*)d_ws;
  unsigned short* frames = (unsigned short*)(ws + off_frames);
  unsigned short* bi     = (unsigned short*)(ws + off_bi);
  unsigned short* wb     = (unsigned short*)(ws + off_wb);
  unsigned short* magT   = (unsigned short*)(ws + off_mag);

  k_frames<<<16384, 256, 0, stream>>>(audio, frames);
  k_basis <<<  576, 256, 0, stream>>>(basis, bi);
  k_w     <<<  180, 256, 0, stream>>>(melw, wb);
  k_stft  <<< 2304, 256, 0, stream>>>(bi, frames, magT);
  k_mel   <<<  256, 256, 0, stream>>>(wb, magT, out);
}

// Round 2
// 123.753 us; speedup vs baseline: 1.3991x; 1.3991x over previous
//
#include <hip/hip_runtime.h>
#include <hip/hip_bf16.h>

typedef short bf16x8 __attribute__((ext_vector_type(8)));
typedef float f32x4  __attribute__((ext_vector_type(4)));

#define T_AUDIO 262144
#define PADL 384
#define CUTOFF 513
#define CPAD 576       // padded mel K (513 -> 576)
#define NMELS 80

__device__ __forceinline__ unsigned short f2bf(float f){
  union { float f; unsigned u; } v; v.f = f;
  return (unsigned short)((v.u + 0x7FFFu + ((v.u >> 16) & 1u)) >> 16);
}

__device__ __forceinline__ void gload_lds16(const void* g, void* l){
  __builtin_amdgcn_global_load_lds(
      (const __attribute__((address_space(1))) unsigned int*)g,
      (__attribute__((address_space(3))) unsigned int*)l, 16, 0, 0);
}

#define LGKM0() do { asm volatile("s_waitcnt lgkmcnt(0)" ::: "memory"); \
                     __builtin_amdgcn_sched_barrier(0); } while(0)
#define VM8()   asm volatile("s_waitcnt vmcnt(8)" ::: "memory")

// ---------- k_frames: frames [32][1024][1024] bf16 + Nyquist col + zero-pad cols ----------
__global__ void k_frames(const float* __restrict__ audio,
                         const float* __restrict__ basis,
                         unsigned short* __restrict__ frames,
                         unsigned short* __restrict__ magT){
  __shared__ float swv[4];
  int tid = threadIdx.x;
  int gid = blockIdx.x * 256 + tid;
  int b   = gid >> 17;
  int rem = gid & 131071;
  int t   = rem >> 7;
  int k0  = (rem & 127) << 3;
  int s0  = t * 256 + k0 - PADL;
  const float* ap = audio + (long)b * T_AUDIO;
  float v[8];
  if (s0 >= 0 && s0 + 7 < T_AUDIO){
    f32x4 a0 = *(const f32x4*)(ap + s0);
    f32x4 a1 = *(const f32x4*)(ap + s0 + 4);
    v[0]=a0[0]; v[1]=a0[1]; v[2]=a0[2]; v[3]=a0[3];
    v[4]=a1[0]; v[5]=a1[1]; v[6]=a1[2]; v[7]=a1[3];
  } else {
    #pragma unroll
    for (int e = 0; e < 8; ++e){
      int s = s0 + e;
      if (s < 0) s = -s;
      if (s >= T_AUDIO) s = 2*(T_AUDIO-1) - s;
      v[e] = ap[s];
    }
  }
  bf16x8 o;
  #pragma unroll
  for (int e = 0; e < 8; ++e) o[e] = (short)f2bf(v[e]);
  *(bf16x8*)(frames + ((long)b << 20) + t * 1024 + k0) = o;

  // Nyquist bin: basis row 512 (= (-1)^k * win[k]), imag part is exactly 0
  const float* nb = basis + 512 * 1024 + k0;
  f32x4 w0 = *(const f32x4*)nb;
  f32x4 w1 = *(const f32x4*)(nb + 4);
  float dot = v[0]*w0[0]+v[1]*w0[1]+v[2]*w0[2]+v[3]*w0[3]
            + v[4]*w1[0]+v[5]*w1[1]+v[6]*w1[2]+v[7]*w1[3];
  #pragma unroll
  for (int off = 32; off; off >>= 1) dot += __shfl_down(dot, off, 64);
  int lane = tid & 63, wid = tid >> 6;
  if (lane == 0) swv[wid] = dot;
  __syncthreads();
  long tg = (long)b * 1024 + t;
  if (tid == 0 || tid == 128){
    float s = (tid == 0) ? (swv[0] + swv[1]) : (swv[2] + swv[3]);
    magT[tg * CPAD + 512] = f2bf(fabsf(s));
  }
  int c = tid & 127;
  if (c < 63) magT[tg * CPAD + 513 + c] = 0;
}

// ---------- k_basis2: interleaved basis [1024][1024] bf16 (c=0..511, re/im pairs) ----------
__global__ void k_basis2(const float* __restrict__ basis, unsigned short* __restrict__ bi){
  int gid = blockIdx.x * 256 + threadIdx.x;   // 1024*128
  int m  = gid >> 7;
  int k0 = (gid & 127) << 3;
  int src = (m >> 1) + CUTOFF * (m & 1);
  f32x4 a0 = *(const f32x4*)(basis + src * 1024 + k0);
  f32x4 a1 = *(const f32x4*)(basis + src * 1024 + k0 + 4);
  bf16x8 o;
  o[0]=(short)f2bf(a0[0]); o[1]=(short)f2bf(a0[1]); o[2]=(short)f2bf(a0[2]); o[3]=(short)f2bf(a0[3]);
  o[4]=(short)f2bf(a1[0]); o[5]=(short)f2bf(a1[1]); o[6]=(short)f2bf(a1[2]); o[7]=(short)f2bf(a1[3]);
  *(bf16x8*)(bi + m * 1024 + k0) = o;
}

// ---------- k_w: mel weights [80][576] bf16, zero-padded ----------
__global__ void k_w(const float* __restrict__ w, unsigned short* __restrict__ wb){
  int gid = blockIdx.x * 256 + threadIdx.x;
  if (gid >= NMELS * CPAD) return;
  int m = gid / CPAD, c = gid % CPAD;
  float v = (c < CUTOFF) ? w[m * CUTOFF + c] : 0.f;
  wb[gid] = f2bf(v);
}

// ---------- k_stft: 256x256 8-phase GEMM + |.| epilogue -> magT [32768][576] bf16 ----------
// C[m][t] = sum_k bi[m][k] * frames[t][k];  mag[m/2][t] via re/im pairs in adjacent acc rows
__launch_bounds__(512, 2)
__global__ void k_stft(const unsigned short* __restrict__ bi,
                       const unsigned short* __restrict__ frames,
                       unsigned short* __restrict__ magT){
  // LDS: [A|B][dbuf(2)][khalf(2)][256 rows][64B = 4 x 16B chunks], 128 KiB total
  __shared__ __align__(16) char AsB[65536];
  __shared__ __align__(16) char BsB[65536];
  const int tid  = threadIdx.x;
  const int lane = tid & 63, wid = tid >> 6;
  const int wm   = wid >> 2, wn = wid & 3;

  int bx = blockIdx.x;
  int sw = ((bx & 7) << 6) | (bx >> 3);       // XCD swizzle (512 % 8 == 0, bijective)
  const int m0 = (sw & 3) << 8;               // 4 M-tiles consecutive per N-tile
  const int n0 = (sw >> 2) << 8;

  // staging addresses: linear LDS dest, source-swizzled global (rule #21)
  const int row_s = wid * 16 + (lane >> 2);                    // row for load j=0 (j=1: +128)
  const int sl16  = (((lane & 3) ^ ((lane >> 3) & 3)) << 4);   // swizzled 16B chunk in k-half
  const char* Ag = (const char*)bi     + (long)(m0 + row_s) * 2048 + sl16;
  const char* Bg = (const char*)frames + (long)(n0 + row_s) * 2048 + sl16;
  char* Al = AsB + wid * 1024;
  char* Bl = BsB + wid * 1024;

  // STAGE one k-half-tile (256 rows x 32 cols): 2 x global_load_lds dwordx4
  #define STAGE(GB, LB, d, ks, kt) do { \
      gload_lds16((GB) + (kt)*128 + (ks)*64,          (LB) + (d)*32768 + (ks)*16384); \
      gload_lds16((GB) + 262144 + (kt)*128 + (ks)*64, (LB) + (d)*32768 + (ks)*16384 + 8192); \
    } while(0)

  // fragment read bases (same XOR swizzle on the read side)
  const int sA16 = (((lane >> 4) ^ ((lane >> 1) & 3)) << 4);
  const char* Ar = AsB + (wm * 128 + (lane & 15)) * 64 + sA16;
  const char* Br = BsB + (wn * 64  + (lane & 15)) * 64 + sA16;

  f32x4 acc[8][4] = {};
  bf16x8 a[4], b0[4], b1[4];

  #define MFMA16(IOFF, BV) do { \
      __builtin_amdgcn_s_setprio(1); \
      _Pragma("unroll") \
      for (int i_ = 0; i_ < 4; ++i_){ \
        _Pragma("unroll") \
        for (int j_ = 0; j_ < 4; ++j_) \
          acc[(IOFF)+i_][j_] = __builtin_amdgcn_mfma_f32_16x16x32_bf16(a[i_], BV[j_], acc[(IOFF)+i_][j_], 0, 0, 0); \
      } \
      __builtin_amdgcn_s_setprio(0); \
    } while(0)

  // prologue: kh0[0], kh1[0], kh0[1] (6 half-tiles, 12 loads); allow 8 in flight
  STAGE(Ag, Al, 0, 0, 0); STAGE(Bg, Bl, 0, 0, 0);
  STAGE(Ag, Al, 0, 1, 0); STAGE(Bg, Bl, 0, 1, 0);
  STAGE(Ag, Al, 1, 0, 1); STAGE(Bg, Bl, 1, 0, 1);
  VM8();
  __builtin_amdgcn_s_barrier();

  for (int kt = 0; kt < 16; ++kt){
    const int d  = kt & 1;
    const int d1 = (kt + 1) & 1;
    const int t1 = (kt + 1) & 15;   // tail wraps: keeps vmcnt accounting steady-state
    const int t2 = (kt + 2) & 15;
    const char* Ab = Ar + d * 32768;
    const char* Bb = Br + d * 32768;

    // p0: read B(ks0), A(mh0,ks0); stage A-kh1[kt+1]
    #pragma unroll
    for (int j = 0; j < 4; ++j) b0[j] = *(const bf16x8*)(Bb + j * 1024);
    #pragma unroll
    for (int i = 0; i < 4; ++i) a[i]  = *(const bf16x8*)(Ab + i * 1024);
    STAGE(Ag, Al, d1, 1, t1);
    __builtin_amdgcn_s_barrier();
    LGKM0();
    MFMA16(0, b0);
    __builtin_amdgcn_s_barrier();

    // p1: read A(mh1,ks0); stage B-kh1[kt+1]; counted vmcnt
    #pragma unroll
    for (int i = 0; i < 4; ++i) a[i] = *(const bf16x8*)(Ab + 4096 + i * 1024);
    STAGE(Bg, Bl, d1, 1, t1);
    __builtin_amdgcn_s_barrier();
    LGKM0();
    MFMA16(4, b0);
    VM8();
    __builtin_amdgcn_s_barrier();

    // p2: read B(ks1), A(mh0,ks1); stage A-kh0[kt+2]
    #pragma unroll
    for (int j = 0; j < 4; ++j) b1[j] = *(const bf16x8*)(Bb + 16384 + j * 1024);
    #pragma unroll
    for (int i = 0; i < 4; ++i) a[i]  = *(const bf16x8*)(Ab + 16384 + i * 1024);
    STAGE(Ag, Al, d, 0, t2);
    __builtin_amdgcn_s_barrier();
    LGKM0();
    MFMA16(0, b1);
    __builtin_amdgcn_s_barrier();

    // p3: read A(mh1,ks1); stage B-kh0[kt+2]; counted vmcnt
    #pragma unroll
    for (int i = 0; i < 4; ++i) a[i] = *(const bf16x8*)(Ab + 16384 + 4096 + i * 1024);
    STAGE(Bg, Bl, d, 0, t2);
    __builtin_amdgcn_s_barrier();
    LGKM0();
    MFMA16(4, b1);
    VM8();
    __builtin_amdgcn_s_barrier();
  }

  // epilogue: re/im pairs in r0/r1 and r2/r3 -> mag, packed 2 x bf16 per u32
  const long tbase = (long)(n0 + wn * 64 + (lane & 15));
  const int  q4 = (lane >> 4) << 2;
  #pragma unroll
  for (int i = 0; i < 8; ++i){
    int mrow = m0 + wm * 128 + (i >> 2) * 64 + (i & 3) * 16 + q4;
    int c0 = mrow >> 1;
    #pragma unroll
    for (int j = 0; j < 4; ++j){
      long t = tbase + j * 16;
      f32x4 dd = acc[i][j];
      float m1 = sqrtf(dd[0]*dd[0] + dd[1]*dd[1]);
      float m2 = sqrtf(dd[2]*dd[2] + dd[3]*dd[3]);
      unsigned pack = (unsigned)f2bf(m1) | ((unsigned)f2bf(m2) << 16);
      *(unsigned*)(magT + t * CPAD + c0) = pack;
    }
  }
  #undef STAGE
  #undef MFMA16
}

// ---------- k_mel: [80][576] x [576][t] + log(clip) -> out [32][80][1024] f32 ----------
__launch_bounds__(256)
__global__ void k_mel(const unsigned short* __restrict__ wb,
                      const unsigned short* __restrict__ magT,
                      float* __restrict__ out){
  __shared__ unsigned short Ws[80 * 32];
  __shared__ unsigned short Ms[128 * 32];
  int tid  = threadIdx.x, lane = tid & 63, wid = tid >> 6;
  int bx   = blockIdx.x;
  int bt   = bx & 7, b = bx >> 3;
  int t0   = bt * 128;
  f32x4 acc[5][2] = {};
  const char* Mb = (const char*)(magT + ((long)b * 1024 + t0) * CPAD);
  const char* Wb = (const char*)wb;

  for (int kt = 0; kt < 18; ++kt){
    int k0b = kt * 64;
    {
      int o = tid * 16;
      gload_lds16(Wb + (o >> 6) * 1152 + k0b + (o & 63), (char*)Ws + wid * 1024);
      if (wid == 0){
        int o2 = 4096 + lane * 16;
        gload_lds16(Wb + (o2 >> 6) * 1152 + k0b + (o2 & 63), (char*)Ws + 4096);
      }
    }
    #pragma unroll
    for (int q = 0; q < 2; ++q){
      int o = (q * 256 + tid) * 16;
      gload_lds16(Mb + (long)(o >> 6) * 1152 + k0b + (o & 63), (char*)Ms + q * 4096 + wid * 1024);
    }
    __syncthreads();
    bf16x8 af[5], bfr[2];
    int kb = (lane >> 4) << 4;
    #pragma unroll
    for (int i = 0; i < 5; ++i)
      af[i] = *(const bf16x8*)((const char*)Ws + (i*16 + (lane & 15)) * 64 + kb);
    #pragma unroll
    for (int j = 0; j < 2; ++j)
      bfr[j] = *(const bf16x8*)((const char*)Ms + (wid*32 + j*16 + (lane & 15)) * 64 + kb);
    #pragma unroll
    for (int i = 0; i < 5; ++i)
      #pragma unroll
      for (int j = 0; j < 2; ++j)
        acc[i][j] = __builtin_amdgcn_mfma_f32_16x16x32_bf16(af[i], bfr[j], acc[i][j], 0, 0, 0);
    __syncthreads();
  }
  #pragma unroll
  for (int i = 0; i < 5; ++i)
    #pragma unroll
    for (int j = 0; j < 2; ++j){
      int m = i*16 + ((lane >> 4) << 2);
      int t = t0 + wid*32 + j*16 + (lane & 15);
      #pragma unroll
      for (int r = 0; r < 4; ++r){
        float v = acc[i][j][r];
        out[((long)b * NMELS + (m + r)) * 1024 + t] = logf(fmaxf(v, 1e-5f));
      }
    }
}

__global__ void k_sentinel(float* out, int n){
  int i = blockIdx.x * 256 + threadIdx.x;
  if (i < n) out[i] = 12345.0f;
}

extern "C" void kernel_launch(void* const* d_in, const int* in_sizes, int n_in,
                              void* d_out, int out_size, void* d_ws, size_t ws_size,
                              hipStream_t stream){
  const float* audio = (const float*)d_in[0];
  const float* basis = (const float*)d_in[1];
  const float* melw  = (const float*)d_in[2];
  float* out = (float*)d_out;

  size_t off_frames = 0;
  size_t off_bi     = off_frames + (size_t)32 * 1024 * 1024 * 2;   // 67,108,864
  size_t off_wb     = off_bi     + (size_t)1024 * 1024 * 2;        // +2,097,152
  size_t off_mag    = off_wb     + (size_t)NMELS * CPAD * 2;       // +92,160
  size_t total      = off_mag    + (size_t)32 * 1024 * CPAD * 2;   // +37,748,736 = 107,046,912

  if (ws_size < total){
    k_sentinel<<<(out_size + 255) / 256, 256, 0, stream>>>(out, out_size);
    return;
  }
  char* ws = (char*)d_ws;
  unsigned short* frames = (unsigned short*)(ws + off_frames);
  unsigned short* bi     = (unsigned short*)(ws + off_bi);
  unsigned short* wb     = (unsigned short*)(ws + off_wb);
  unsigned short* magT   = (unsigned short*)(ws + off_mag);

  k_frames<<<16384, 256, 0, stream>>>(audio, basis, frames, magT);
  k_basis2<<<  512, 256, 0, stream>>>(basis, bi);
  k_w     <<<  180, 256, 0, stream>>>(melw, wb);
  k_stft  <<<  512, 512, 0, stream>>>(bi, frames, magT);
  k_mel   <<<  256, 256, 0, stream>>>(wb, magT, out);
}

// Round 3
// 121.941 us; speedup vs baseline: 1.4199x; 1.0149x over previous
//
#include <hip/hip_runtime.h>
#include <hip/hip_bf16.h>

typedef short bf16x8 __attribute__((ext_vector_type(8)));
typedef float f32x4  __attribute__((ext_vector_type(4)));

#define T_AUDIO 262144
#define PADL 384
#define CUTOFF 513
#define CPAD 576       // padded mel K (513 -> 576)
#define NMELS 80

__device__ __forceinline__ unsigned short f2bf(float f){
  union { float f; unsigned u; } v; v.f = f;
  return (unsigned short)((v.u + 0x7FFFu + ((v.u >> 16) & 1u)) >> 16);
}

__device__ __forceinline__ void gload_lds16(const void* g, void* l){
  __builtin_amdgcn_global_load_lds(
      (const __attribute__((address_space(1))) unsigned int*)g,
      (__attribute__((address_space(3))) unsigned int*)l, 16, 0, 0);
}

// ---------- k_frames: frames [32][1024][1024] bf16 + Nyquist col + zero-pad cols ----------
__global__ void k_frames(const float* __restrict__ audio,
                         const float* __restrict__ basis,
                         unsigned short* __restrict__ frames,
                         unsigned short* __restrict__ magT){
  __shared__ float swv[4];
  int tid = threadIdx.x;
  int gid = blockIdx.x * 256 + tid;
  int b   = gid >> 17;
  int rem = gid & 131071;
  int t   = rem >> 7;
  int k0  = (rem & 127) << 3;
  int s0  = t * 256 + k0 - PADL;
  const float* ap = audio + (long)b * T_AUDIO;
  float v[8];
  if (s0 >= 0 && s0 + 7 < T_AUDIO){
    f32x4 a0 = *(const f32x4*)(ap + s0);
    f32x4 a1 = *(const f32x4*)(ap + s0 + 4);
    v[0]=a0[0]; v[1]=a0[1]; v[2]=a0[2]; v[3]=a0[3];
    v[4]=a1[0]; v[5]=a1[1]; v[6]=a1[2]; v[7]=a1[3];
  } else {
    #pragma unroll
    for (int e = 0; e < 8; ++e){
      int s = s0 + e;
      if (s < 0) s = -s;
      if (s >= T_AUDIO) s = 2*(T_AUDIO-1) - s;
      v[e] = ap[s];
    }
  }
  bf16x8 o;
  #pragma unroll
  for (int e = 0; e < 8; ++e) o[e] = (short)f2bf(v[e]);
  *(bf16x8*)(frames + ((long)b << 20) + t * 1024 + k0) = o;

  // Nyquist bin: basis row 512 (= (-1)^k * win[k]), imag part is exactly 0
  const float* nb = basis + 512 * 1024 + k0;
  f32x4 w0 = *(const f32x4*)nb;
  f32x4 w1 = *(const f32x4*)(nb + 4);
  float dot = v[0]*w0[0]+v[1]*w0[1]+v[2]*w0[2]+v[3]*w0[3]
            + v[4]*w1[0]+v[5]*w1[1]+v[6]*w1[2]+v[7]*w1[3];
  #pragma unroll
  for (int off = 32; off; off >>= 1) dot += __shfl_down(dot, off, 64);
  int lane = tid & 63, wid = tid >> 6;
  if (lane == 0) swv[wid] = dot;
  __syncthreads();
  long tg = (long)b * 1024 + t;
  if (tid == 0 || tid == 128){
    float s = (tid == 0) ? (swv[0] + swv[1]) : (swv[2] + swv[3]);
    magT[tg * CPAD + 512] = f2bf(fabsf(s));
  }
  int c = tid & 127;
  if (c < 63) magT[tg * CPAD + 513 + c] = 0;
}

// ---------- k_basis2: interleaved basis [1024][1024] bf16 (c=0..511, re/im pairs) ----------
__global__ void k_basis2(const float* __restrict__ basis, unsigned short* __restrict__ bi){
  int gid = blockIdx.x * 256 + threadIdx.x;   // 1024*128
  int m  = gid >> 7;
  int k0 = (gid & 127) << 3;
  int src = (m >> 1) + CUTOFF * (m & 1);
  f32x4 a0 = *(const f32x4*)(basis + src * 1024 + k0);
  f32x4 a1 = *(const f32x4*)(basis + src * 1024 + k0 + 4);
  bf16x8 o;
  o[0]=(short)f2bf(a0[0]); o[1]=(short)f2bf(a0[1]); o[2]=(short)f2bf(a0[2]); o[3]=(short)f2bf(a0[3]);
  o[4]=(short)f2bf(a1[0]); o[5]=(short)f2bf(a1[1]); o[6]=(short)f2bf(a1[2]); o[7]=(short)f2bf(a1[3]);
  *(bf16x8*)(bi + m * 1024 + k0) = o;
}

// ---------- k_w: mel weights [80][576] bf16, zero-padded ----------
__global__ void k_w(const float* __restrict__ w, unsigned short* __restrict__ wb){
  int gid = blockIdx.x * 256 + threadIdx.x;
  if (gid >= NMELS * CPAD) return;
  int m = gid / CPAD, c = gid % CPAD;
  float v = (c < CUTOFF) ? w[m * CUTOFF + c] : 0.f;
  wb[gid] = f2bf(v);
}

// ---------- k_stft: 256x256 GEMM, 1 barrier/K-tile, frag-pipelined ----------
// C[m][t] = sum_k bi[m][k] * frames[t][k];  mag[m/2][t] via re/im pairs in adjacent acc rows
__launch_bounds__(512, 2)
__global__ void k_stft(const unsigned short* __restrict__ bi,
                       const unsigned short* __restrict__ frames,
                       unsigned short* __restrict__ magT){
  // LDS: [A|B][dbuf(2)][khalf(2)][256 rows][64B = 4 x 16B chunks], 128 KiB total
  __shared__ __align__(16) char AsB[65536];
  __shared__ __align__(16) char BsB[65536];
  const int tid  = threadIdx.x;
  const int lane = tid & 63, wid = tid >> 6;
  const int wm   = wid >> 2, wn = wid & 3;

  int bx = blockIdx.x;
  int sw = ((bx & 7) << 6) | (bx >> 3);       // XCD swizzle (512 % 8 == 0, bijective)
  const int m0 = (sw & 3) << 8;               // 4 M-tiles consecutive per N-tile
  const int n0 = (sw >> 2) << 8;

  // staging addresses: linear LDS dest, source-swizzled global (rule #21)
  const int row_s = wid * 16 + (lane >> 2);                    // row for load j=0 (j=1: +128)
  const int sl16  = (((lane & 3) ^ ((lane >> 3) & 3)) << 4);   // swizzled 16B chunk in k-half
  const char* Ag = (const char*)bi     + (long)(m0 + row_s) * 2048 + sl16;
  const char* Bg = (const char*)frames + (long)(n0 + row_s) * 2048 + sl16;
  char* Al = AsB + wid * 1024;
  char* Bl = BsB + wid * 1024;

  // STAGE one k-half-tile (256 rows x 32 cols): 2 x global_load_lds dwordx4
  #define STAGE(GB, LB, d, ks, kt) do { \
      gload_lds16((GB) + (kt)*128 + (ks)*64,          (LB) + (d)*32768 + (ks)*16384); \
      gload_lds16((GB) + 262144 + (kt)*128 + (ks)*64, (LB) + (d)*32768 + (ks)*16384 + 8192); \
    } while(0)

  // fragment read bases (same XOR swizzle on the read side)
  const int sA16 = (((lane >> 4) ^ ((lane >> 1) & 3)) << 4);
  const char* Ar = AsB + (wm * 128 + (lane & 15)) * 64 + sA16;
  const char* Br = BsB + (wn * 64  + (lane & 15)) * 64 + sA16;

  f32x4 acc[8][4] = {};
  bf16x8 a0[8], a1[8], bq[4];

  // prologue: stage K-tile 0 into d=0 (8 loads), drain, barrier
  STAGE(Ag, Al, 0, 0, 0); STAGE(Bg, Bl, 0, 0, 0);
  STAGE(Ag, Al, 0, 1, 0); STAGE(Bg, Bl, 0, 1, 0);
  asm volatile("s_waitcnt vmcnt(0)" ::: "memory");
  __builtin_amdgcn_s_barrier();

  #pragma unroll
  for (int kt = 0; kt < 16; ++kt){
    const int d  = kt & 1;
    const int d1 = d ^ 1;
    const int t1 = (kt + 1) & 15;   // wrap on last iter: keeps accounting uniform
    const char* Ab = Ar + d * 32768;
    const char* Bb = Br + d * 32768;

    // ks0 frags (12 ds_read_b128)
    #pragma unroll
    for (int j = 0; j < 4; ++j) bq[j] = *(const bf16x8*)(Bb + j * 1024);
    #pragma unroll
    for (int i = 0; i < 8; ++i) a0[i] = *(const bf16x8*)(Ab + i * 1024);
    // stage K-tile kt+1 into the other buffer (8 global_load_lds)
    STAGE(Ag, Al, d1, 0, t1); STAGE(Bg, Bl, d1, 0, t1);
    STAGE(Ag, Al, d1, 1, t1); STAGE(Bg, Bl, d1, 1, t1);
    // ks1 A-frags early (8 ds_read_b128, stay in flight during ks0 MFMAs)
    #pragma unroll
    for (int i = 0; i < 8; ++i) a1[i] = *(const bf16x8*)(Ab + 16384 + i * 1024);

    asm volatile("s_waitcnt lgkmcnt(8)" ::: "memory");   // ks0's 12 done; ks1-A in flight
    __builtin_amdgcn_sched_barrier(0);
    __builtin_amdgcn_s_setprio(1);
    #pragma unroll
    for (int j = 0; j < 4; ++j)       // j-outer: bq[j] dies early for reuse below
      #pragma unroll
      for (int i = 0; i < 8; ++i)
        acc[i][j] = __builtin_amdgcn_mfma_f32_16x16x32_bf16(a0[i], bq[j], acc[i][j], 0, 0, 0);
    __builtin_amdgcn_s_setprio(0);

    // ks1 B-frags into the same regs (4 ds_read_b128)
    #pragma unroll
    for (int j = 0; j < 4; ++j) bq[j] = *(const bf16x8*)(Bb + 16384 + j * 1024);
    asm volatile("s_waitcnt lgkmcnt(0)" ::: "memory");
    __builtin_amdgcn_sched_barrier(0);
    __builtin_amdgcn_s_setprio(1);
    #pragma unroll
    for (int j = 0; j < 4; ++j)
      #pragma unroll
      for (int i = 0; i < 8; ++i)
        acc[i][j] = __builtin_amdgcn_mfma_f32_16x16x32_bf16(a1[i], bq[j], acc[i][j], 0, 0, 0);
    __builtin_amdgcn_s_setprio(0);

    // next tile fully staged (issued a full K-tile ago -> ~no stall), one barrier
    asm volatile("s_waitcnt vmcnt(0)" ::: "memory");
    __builtin_amdgcn_s_barrier();
  }

  // epilogue: re/im pairs in r0/r1 and r2/r3 -> mag, packed 2 x bf16 per u32
  const long tbase = (long)(n0 + wn * 64 + (lane & 15));
  const int  q4 = (lane >> 4) << 2;
  #pragma unroll
  for (int i = 0; i < 8; ++i){
    int mrow = m0 + wm * 128 + (i >> 2) * 64 + (i & 3) * 16 + q4;
    int c0 = mrow >> 1;
    #pragma unroll
    for (int j = 0; j < 4; ++j){
      long t = tbase + j * 16;
      f32x4 dd = acc[i][j];
      float m1 = sqrtf(dd[0]*dd[0] + dd[1]*dd[1]);
      float m2 = sqrtf(dd[2]*dd[2] + dd[3]*dd[3]);
      unsigned pack = (unsigned)f2bf(m1) | ((unsigned)f2bf(m2) << 16);
      *(unsigned*)(magT + t * CPAD + c0) = pack;
    }
  }
  #undef STAGE
}

// ---------- k_mel: [80][576] x [576][t] + log(clip) -> out [32][80][1024] f32 ----------
__launch_bounds__(256)
__global__ void k_mel(const unsigned short* __restrict__ wb,
                      const unsigned short* __restrict__ magT,
                      float* __restrict__ out){
  __shared__ unsigned short Ws[80 * 32];
  __shared__ unsigned short Ms[128 * 32];
  int tid  = threadIdx.x, lane = tid & 63, wid = tid >> 6;
  int bx   = blockIdx.x;
  int bt   = bx & 7, b = bx >> 3;
  int t0   = bt * 128;
  f32x4 acc[5][2] = {};
  const char* Mb = (const char*)(magT + ((long)b * 1024 + t0) * CPAD);
  const char* Wb = (const char*)wb;

  for (int kt = 0; kt < 18; ++kt){
    int k0b = kt * 64;
    {
      int o = tid * 16;
      gload_lds16(Wb + (o >> 6) * 1152 + k0b + (o & 63), (char*)Ws + wid * 1024);
      if (wid == 0){
        int o2 = 4096 + lane * 16;
        gload_lds16(Wb + (o2 >> 6) * 1152 + k0b + (o2 & 63), (char*)Ws + 4096);
      }
    }
    #pragma unroll
    for (int q = 0; q < 2; ++q){
      int o = (q * 256 + tid) * 16;
      gload_lds16(Mb + (long)(o >> 6) * 1152 + k0b + (o & 63), (char*)Ms + q * 4096 + wid * 1024);
    }
    __syncthreads();
    bf16x8 af[5], bfr[2];
    int kb = (lane >> 4) << 4;
    #pragma unroll
    for (int i = 0; i < 5; ++i)
      af[i] = *(const bf16x8*)((const char*)Ws + (i*16 + (lane & 15)) * 64 + kb);
    #pragma unroll
    for (int j = 0; j < 2; ++j)
      bfr[j] = *(const bf16x8*)((const char*)Ms + (wid*32 + j*16 + (lane & 15)) * 64 + kb);
    #pragma unroll
    for (int i = 0; i < 5; ++i)
      #pragma unroll
      for (int j = 0; j < 2; ++j)
        acc[i][j] = __builtin_amdgcn_mfma_f32_16x16x32_bf16(af[i], bfr[j], acc[i][j], 0, 0, 0);
    __syncthreads();
  }
  #pragma unroll
  for (int i = 0; i < 5; ++i)
    #pragma unroll
    for (int j = 0; j < 2; ++j){
      int m = i*16 + ((lane >> 4) << 2);
      int t = t0 + wid*32 + j*16 + (lane & 15);
      #pragma unroll
      for (int r = 0; r < 4; ++r){
        float v = acc[i][j][r];
        out[((long)b * NMELS + (m + r)) * 1024 + t] = logf(fmaxf(v, 1e-5f));
      }
    }
}

__global__ void k_sentinel(float* out, int n){
  int i = blockIdx.x * 256 + threadIdx.x;
  if (i < n) out[i] = 12345.0f;
}

extern "C" void kernel_launch(void* const* d_in, const int* in_sizes, int n_in,
                              void* d_out, int out_size, void* d_ws, size_t ws_size,
                              hipStream_t stream){
  const float* audio = (const float*)d_in[0];
  const float* basis = (const float*)d_in[1];
  const float* melw  = (const float*)d_in[2];
  float* out = (float*)d_out;

  size_t off_frames = 0;
  size_t off_bi     = off_frames + (size_t)32 * 1024 * 1024 * 2;   // 67,108,864
  size_t off_wb     = off_bi     + (size_t)1024 * 1024 * 2;        // +2,097,152
  size_t off_mag    = off_wb     + (size_t)NMELS * CPAD * 2;       // +92,160
  size_t total      = off_mag    + (size_t)32 * 1024 * CPAD * 2;   // +37,748,736 = 107,046,912

  if (ws_size < total){
    k_sentinel<<<(out_size + 255) / 256, 256, 0, stream>>>(out, out_size);
    return;
  }
  char* ws = (char*)d_ws;
  unsigned short* frames = (unsigned short*)(ws + off_frames);
  unsigned short* bi     = (unsigned short*)(ws + off_bi);
  unsigned short* wb     = (unsigned short*)(ws + off_wb);
  unsigned short* magT   = (unsigned short*)(ws + off_mag);

  k_frames<<<16384, 256, 0, stream>>>(audio, basis, frames, magT);
  k_basis2<<<  512, 256, 0, stream>>>(basis, bi);
  k_w     <<<  180, 256, 0, stream>>>(melw, wb);
  k_stft  <<<  512, 512, 0, stream>>>(bi, frames, magT);
  k_mel   <<<  256, 256, 0, stream>>>(wb, magT, out);
}

// Round 4
// 116.495 us; speedup vs baseline: 1.4863x; 1.0468x over previous
//
#include <hip/hip_runtime.h>
#include <hip/hip_bf16.h>

typedef short bf16x8 __attribute__((ext_vector_type(8)));
typedef float f32x4  __attribute__((ext_vector_type(4)));

#define T_AUDIO 262144
#define PADL 384
#define CUTOFF 513
#define CPAD 576       // padded mel K (513 -> 576)
#define NMELS 80

__device__ __forceinline__ unsigned short f2bf(float f){
  union { float f; unsigned u; } v; v.f = f;
  return (unsigned short)((v.u + 0x7FFFu + ((v.u >> 16) & 1u)) >> 16);
}

__device__ __forceinline__ void gload_lds16(const void* g, void* l){
  __builtin_amdgcn_global_load_lds(
      (const __attribute__((address_space(1))) unsigned int*)g,
      (__attribute__((address_space(3))) unsigned int*)l, 16, 0, 0);
}

#define BAR  __builtin_amdgcn_s_barrier()
#define WLG0 do{ asm volatile("s_waitcnt lgkmcnt(0)":::"memory"); \
                 __builtin_amdgcn_sched_barrier(0); }while(0)
#define WLG8 asm volatile("s_waitcnt lgkmcnt(8)":::"memory")
#define WVM6 asm volatile("s_waitcnt vmcnt(6)":::"memory")

// ---------- k_frames: frames [32][1024][1024] bf16 + Nyquist col + zero-pad cols ----------
__global__ void k_frames(const float* __restrict__ audio,
                         const float* __restrict__ basis,
                         unsigned short* __restrict__ frames,
                         unsigned short* __restrict__ magT){
  __shared__ float swv[4];
  int tid = threadIdx.x;
  int gid = blockIdx.x * 256 + tid;
  int b   = gid >> 17;
  int rem = gid & 131071;
  int t   = rem >> 7;
  int k0  = (rem & 127) << 3;
  int s0  = t * 256 + k0 - PADL;
  const float* ap = audio + (long)b * T_AUDIO;
  float v[8];
  if (s0 >= 0 && s0 + 7 < T_AUDIO){
    f32x4 a0 = *(const f32x4*)(ap + s0);
    f32x4 a1 = *(const f32x4*)(ap + s0 + 4);
    v[0]=a0[0]; v[1]=a0[1]; v[2]=a0[2]; v[3]=a0[3];
    v[4]=a1[0]; v[5]=a1[1]; v[6]=a1[2]; v[7]=a1[3];
  } else {
    #pragma unroll
    for (int e = 0; e < 8; ++e){
      int s = s0 + e;
      if (s < 0) s = -s;
      if (s >= T_AUDIO) s = 2*(T_AUDIO-1) - s;
      v[e] = ap[s];
    }
  }
  bf16x8 o;
  #pragma unroll
  for (int e = 0; e < 8; ++e) o[e] = (short)f2bf(v[e]);
  *(bf16x8*)(frames + ((long)b << 20) + t * 1024 + k0) = o;

  // Nyquist bin: basis row 512 (= (-1)^k * win[k]), imag part is exactly 0
  const float* nb = basis + 512 * 1024 + k0;
  f32x4 w0 = *(const f32x4*)nb;
  f32x4 w1 = *(const f32x4*)(nb + 4);
  float dot = v[0]*w0[0]+v[1]*w0[1]+v[2]*w0[2]+v[3]*w0[3]
            + v[4]*w1[0]+v[5]*w1[1]+v[6]*w1[2]+v[7]*w1[3];
  #pragma unroll
  for (int off = 32; off; off >>= 1) dot += __shfl_down(dot, off, 64);
  int lane = tid & 63, wid = tid >> 6;
  if (lane == 0) swv[wid] = dot;
  __syncthreads();
  long tg = (long)b * 1024 + t;
  if (tid == 0 || tid == 128){
    float s = (tid == 0) ? (swv[0] + swv[1]) : (swv[2] + swv[3]);
    magT[tg * CPAD + 512] = f2bf(fabsf(s));
  }
  int c = tid & 127;
  if (c < 63) magT[tg * CPAD + 513 + c] = 0;
}

// ---------- k_basis2: interleaved basis [1024][1024] bf16 (c=0..511, re/im pairs) ----------
__global__ void k_basis2(const float* __restrict__ basis, unsigned short* __restrict__ bi){
  int gid = blockIdx.x * 256 + threadIdx.x;   // 1024*128
  int m  = gid >> 7;
  int k0 = (gid & 127) << 3;
  int src = (m >> 1) + CUTOFF * (m & 1);
  f32x4 a0 = *(const f32x4*)(basis + src * 1024 + k0);
  f32x4 a1 = *(const f32x4*)(basis + src * 1024 + k0 + 4);
  bf16x8 o;
  o[0]=(short)f2bf(a0[0]); o[1]=(short)f2bf(a0[1]); o[2]=(short)f2bf(a0[2]); o[3]=(short)f2bf(a0[3]);
  o[4]=(short)f2bf(a1[0]); o[5]=(short)f2bf(a1[1]); o[6]=(short)f2bf(a1[2]); o[7]=(short)f2bf(a1[3]);
  *(bf16x8*)(bi + m * 1024 + k0) = o;
}

// ---------- k_w: mel weights [80][576] bf16, zero-padded ----------
__global__ void k_w(const float* __restrict__ w, unsigned short* __restrict__ wb){
  int gid = blockIdx.x * 256 + threadIdx.x;
  if (gid >= NMELS * CPAD) return;
  int m = gid / CPAD, c = gid % CPAD;
  float v = (c < CUTOFF) ? w[m * CUTOFF + c] : 0.f;
  wb[gid] = f2bf(v);
}

// ---------- k_stft: 256x256 GEMM, m201-style 8-phase schedule ----------
// LDS: A at [d*32768 + h*16384 + (R&63)*128 + swz]  (h = row>>7, s-half in +8192)
//      B at 65536 + same.  One K-tile (K=64) per dbuf; dbuf = kt&1 (static).
__launch_bounds__(512, 2)
__global__ void k_stft(const unsigned short* __restrict__ bi,
                       const unsigned short* __restrict__ frames,
                       unsigned short* __restrict__ magT){
  __shared__ __align__(16) char LDS[131072];
  const int tid = threadIdx.x;
  const int l   = tid & 63, w = tid >> 6;
  const int wm  = w >> 2, wn = w & 3;

  int bx = blockIdx.x;
  int sw = ((bx & 7) << 6) | (bx >> 3);       // XCD swizzle (512 % 8 == 0, bijective)
  const int m0 = (sw & 3) << 8;
  const int n0 = (sw >> 2) << 8;

  // ---- read-side bases (chunk XOR swizzle: c ^= row&7; row&7 == l&7 for all frags) ----
  const int ch0 = (((l >> 4)     ^ (l & 7)) << 4);   // k-slice 0 chunk
  const int ch1 = (((4 + (l>>4)) ^ (l & 7)) << 4);   // k-slice 1 chunk
  const char* ArS0 = LDS + wm * 16384 + (l & 15) * 128 + ch0;
  const char* ArS1 = LDS + wm * 16384 + (l & 15) * 128 + ch1;
  const char* BrS0 = LDS + 65536 + (wn >> 1) * 16384 + ((wn & 1) * 64 + (l & 15)) * 128 + ch0;
  const char* BrS1 = LDS + 65536 + (wn >> 1) * 16384 + ((wn & 1) * 64 + (l & 15)) * 128 + ch1;

  // ---- stage-side: per-lane pre-swizzled global source, linear LDS dest ----
  const int srow = w * 8 + (l >> 3);                         // row within 64-row unit
  const int sswz = (((l & 7) ^ (l >> 3)) << 4);              // source chunk
  const char* Ag = (const char*)bi     + (long)(m0 + srow) * 2048 + sswz;
  const char* Bg = (const char*)frames + (long)(n0 + srow) * 2048 + sswz;
  char* Ald = LDS + w * 1024;            // + d*32768 + h*16384 + s*8192
  char* Bld = LDS + 65536 + w * 1024;    // + d*32768 + u*8192

  // unit stages: A(h,s) = rows h*128+s*64+[0,64); B(u) = rows u*64+[0,64)
  #define STA(d,h,s,gk) gload_lds16(Ag + (h)*262144 + (s)*131072 + (gk), \
                                    Ald + (d)*32768 + (h)*16384 + (s)*8192)
  #define STB(d,u,gk)   gload_lds16(Bg + (u)*131072 + (gk), \
                                    Bld + (d)*32768 + (u)*8192)

  f32x4 acc[8][4] = {};
  bf16x8 as0[4], as1[4], b0s0[2], b0s1[2], b1s0[2], b1s1[2];

  #define RDA(doff, f0) do{ _Pragma("unroll") \
    for (int i_=0;i_<4;++i_){ as0[i_] = *(const bf16x8*)(ArS0 + (doff) + ((f0)+i_)*2048); \
                              as1[i_] = *(const bf16x8*)(ArS1 + (doff) + ((f0)+i_)*2048);} }while(0)
  #define RDB(d0v,d1v,doff,f0) do{ _Pragma("unroll") \
    for (int j_=0;j_<2;++j_){ d0v[j_] = *(const bf16x8*)(BrS0 + (doff) + ((f0)+j_)*2048); \
                              d1v[j_] = *(const bf16x8*)(BrS1 + (doff) + ((f0)+j_)*2048);} }while(0)
  #define MM(i0,j0,B0,B1) do{ __builtin_amdgcn_s_setprio(1); _Pragma("unroll") \
    for (int i_=0;i_<4;++i_){ _Pragma("unroll") \
      for (int j_=0;j_<2;++j_){ \
        acc[(i0)+i_][(j0)+j_] = __builtin_amdgcn_mfma_f32_16x16x32_bf16(as0[i_], B0[j_], acc[(i0)+i_][(j0)+j_], 0,0,0); \
        acc[(i0)+i_][(j0)+j_] = __builtin_amdgcn_mfma_f32_16x16x32_bf16(as1[i_], B1[j_], acc[(i0)+i_][(j0)+j_], 0,0,0); } } \
    __builtin_amdgcn_s_setprio(0); }while(0)

  // ---- prologue: Kt0 full (8), Kt1 all but A-s1 (6); Kt0 guaranteed in ----
  STA(0,0,0,0); STA(0,1,0,0); STA(0,0,1,0); STA(0,1,1,0);
  STB(0,0,0);   STB(0,1,0);   STB(0,2,0);   STB(0,3,0);
  STA(1,0,0,128); STA(1,1,0,128);
  STB(1,0,128); STB(1,1,128); STB(1,2,128); STB(1,3,128);
  WVM6;
  BAR;

  for (int it = 0; it < 8; ++it){
    const int gk1 = it * 256 + 128;
    const int gk2 = (it * 256 + 256) & 2047;   // wraps only on last iter (harmless)
    const int gk3 = (it * 256 + 384) & 2047;

    // p1: rd A0,B01 [d0]; stage A-s1 pair of Kt(2i+1) [d1]
    RDB(b0s0, b0s1, 0, 0);
    RDA(0, 0);
    STA(1,0,1,gk1); STA(1,1,1,gk1);
    WLG8;
    BAR; WLG0; MM(0,0,b0s0,b0s1); BAR;

    // p2: rd B23 [d0]; stage A-s0 pair of Kt(2i+2) [d0]
    RDB(b1s0, b1s1, 0, 2);
    STA(0,0,0,gk2); STA(0,1,0,gk2);
    BAR; WLG0; MM(0,2,b1s0,b1s1); BAR;

    // p3: rd A1 [d0]; stage B units 0,1 of Kt(2i+2) [d0]
    RDA(0, 4);
    STB(0,0,gk2); STB(0,1,gk2);
    BAR; WLG0; MM(4,2,b1s0,b1s1); BAR;

    // p4: stage B units 2,3 of Kt(2i+2); counted vmcnt
    STB(0,2,gk2); STB(0,3,gk2);
    WVM6;
    BAR; MM(4,0,b0s0,b0s1); BAR;

    // p5: rd A0,B01 [d1]; stage A-s1 pair of Kt(2i+2) [d0]
    RDB(b0s0, b0s1, 32768, 0);
    RDA(32768, 0);
    STA(0,0,1,gk2); STA(0,1,1,gk2);
    WLG8;
    BAR; WLG0; MM(0,0,b0s0,b0s1); BAR;

    // p6: rd B23 [d1]; stage A-s0 pair of Kt(2i+3) [d1]
    RDB(b1s0, b1s1, 32768, 2);
    STA(1,0,0,gk3); STA(1,1,0,gk3);
    BAR; WLG0; MM(0,2,b1s0,b1s1); BAR;

    // p7: rd A1 [d1]; stage B units 0,1 of Kt(2i+3) [d1]
    RDA(32768, 4);
    STB(1,0,gk3); STB(1,1,gk3);
    BAR; WLG0; MM(4,2,b1s0,b1s1); BAR;

    // p8: stage B units 2,3 of Kt(2i+3); counted vmcnt
    STB(1,2,gk3); STB(1,3,gk3);
    WVM6;
    BAR; MM(4,0,b0s0,b0s1); BAR;
  }

  // epilogue: re/im pairs in r0/r1 and r2/r3 -> mag, packed 2 x bf16 per u32
  const long tbase = (long)(n0 + wn * 64 + (l & 15));
  const int  q4 = (l >> 4) << 2;
  #pragma unroll
  for (int i = 0; i < 8; ++i){
    int mrow = m0 + wm * 128 + i * 16 + q4;
    int c0 = mrow >> 1;
    #pragma unroll
    for (int j = 0; j < 4; ++j){
      long t = tbase + j * 16;
      f32x4 dd = acc[i][j];
      float m1 = sqrtf(dd[0]*dd[0] + dd[1]*dd[1]);
      float m2 = sqrtf(dd[2]*dd[2] + dd[3]*dd[3]);
      unsigned pack = (unsigned)f2bf(m1) | ((unsigned)f2bf(m2) << 16);
      *(unsigned*)(magT + t * CPAD + c0) = pack;
    }
  }
  #undef STA
  #undef STB
  #undef RDA
  #undef RDB
  #undef MM
}

// ---------- k_mel: [80][576] x [576][t] + log(clip) -> out [32][80][1024] f32 ----------
__launch_bounds__(256)
__global__ void k_mel(const unsigned short* __restrict__ wb,
                      const unsigned short* __restrict__ magT,
                      float* __restrict__ out){
  __shared__ unsigned short Ws[80 * 32];
  __shared__ unsigned short Ms[128 * 32];
  int tid  = threadIdx.x, lane = tid & 63, wid = tid >> 6;
  int bx   = blockIdx.x;
  int bt   = bx & 7, b = bx >> 3;
  int t0   = bt * 128;
  f32x4 acc[5][2] = {};
  const char* Mb = (const char*)(magT + ((long)b * 1024 + t0) * CPAD);
  const char* Wb = (const char*)wb;

  for (int kt = 0; kt < 18; ++kt){
    int k0b = kt * 64;
    {
      int o = tid * 16;
      gload_lds16(Wb + (o >> 6) * 1152 + k0b + (o & 63), (char*)Ws + wid * 1024);
      if (wid == 0){
        int o2 = 4096 + lane * 16;
        gload_lds16(Wb + (o2 >> 6) * 1152 + k0b + (o2 & 63), (char*)Ws + 4096);
      }
    }
    #pragma unroll
    for (int q = 0; q < 2; ++q){
      int o = (q * 256 + tid) * 16;
      gload_lds16(Mb + (long)(o >> 6) * 1152 + k0b + (o & 63), (char*)Ms + q * 4096 + wid * 1024);
    }
    __syncthreads();
    bf16x8 af[5], bfr[2];
    int kb = (lane >> 4) << 4;
    #pragma unroll
    for (int i = 0; i < 5; ++i)
      af[i] = *(const bf16x8*)((const char*)Ws + (i*16 + (lane & 15)) * 64 + kb);
    #pragma unroll
    for (int j = 0; j < 2; ++j)
      bfr[j] = *(const bf16x8*)((const char*)Ms + (wid*32 + j*16 + (lane & 15)) * 64 + kb);
    #pragma unroll
    for (int i = 0; i < 5; ++i)
      #pragma unroll
      for (int j = 0; j < 2; ++j)
        acc[i][j] = __builtin_amdgcn_mfma_f32_16x16x32_bf16(af[i], bfr[j], acc[i][j], 0, 0, 0);
    __syncthreads();
  }
  #pragma unroll
  for (int i = 0; i < 5; ++i)
    #pragma unroll
    for (int j = 0; j < 2; ++j){
      int m = i*16 + ((lane >> 4) << 2);
      int t = t0 + wid*32 + j*16 + (lane & 15);
      #pragma unroll
      for (int r = 0; r < 4; ++r){
        float v = acc[i][j][r];
        out[((long)b * NMELS + (m + r)) * 1024 + t] = logf(fmaxf(v, 1e-5f));
      }
    }
}

__global__ void k_sentinel(float* out, int n){
  int i = blockIdx.x * 256 + threadIdx.x;
  if (i < n) out[i] = 12345.0f;
}

extern "C" void kernel_launch(void* const* d_in, const int* in_sizes, int n_in,
                              void* d_out, int out_size, void* d_ws, size_t ws_size,
                              hipStream_t stream){
  const float* audio = (const float*)d_in[0];
  const float* basis = (const float*)d_in[1];
  const float* melw  = (const float*)d_in[2];
  float* out = (float*)d_out;

  size_t off_frames = 0;
  size_t off_bi     = off_frames + (size_t)32 * 1024 * 1024 * 2;   // 67,108,864
  size_t off_wb     = off_bi     + (size_t)1024 * 1024 * 2;        // +2,097,152
  size_t off_mag    = off_wb     + (size_t)NMELS * CPAD * 2;       // +92,160
  size_t total      = off_mag    + (size_t)32 * 1024 * CPAD * 2;   // +37,748,736 = 107,046,912

  if (ws_size < total){
    k_sentinel<<<(out_size + 255) / 256, 256, 0, stream>>>(out, out_size);
    return;
  }
  char* ws = (char*)d_ws;
  unsigned short* frames = (unsigned short*)(ws + off_frames);
  unsigned short* bi     = (unsigned short*)(ws + off_bi);
  unsigned short* wb     = (unsigned short*)(ws + off_wb);
  unsigned short* magT   = (unsigned short*)(ws + off_mag);

  k_frames<<<16384, 256, 0, stream>>>(audio, basis, frames, magT);
  k_basis2<<<  512, 256, 0, stream>>>(basis, bi);
  k_w     <<<  180, 256, 0, stream>>>(melw, wb);
  k_stft  <<<  512, 512, 0, stream>>>(bi, frames, magT);
  k_mel   <<<  256, 256, 0, stream>>>(wb, magT, out);
}

// Round 5
// 102.048 us; speedup vs baseline: 1.6967x; 1.1416x over previous
//
#include <hip/hip_runtime.h>
#include <hip/hip_bf16.h>

typedef short bf16x8 __attribute__((ext_vector_type(8)));
typedef short bf16x4 __attribute__((ext_vector_type(4)));
typedef float f32x4  __attribute__((ext_vector_type(4)));

#define T_AUDIO 262144
#define PADL 384
#define CUTOFF 513
#define CPAD 576       // padded mel K (513 -> 576)
#define NMELS 80

__device__ __forceinline__ unsigned short f2bf(float f){
  union { float f; unsigned u; } v; v.f = f;
  return (unsigned short)((v.u + 0x7FFFu + ((v.u >> 16) & 1u)) >> 16);
}

__device__ __forceinline__ void gload_lds16(const void* g, void* l){
  __builtin_amdgcn_global_load_lds(
      (const __attribute__((address_space(1))) unsigned int*)g,
      (__attribute__((address_space(3))) unsigned int*)l, 16, 0, 0);
}

#define BAR  __builtin_amdgcn_s_barrier()
#define WLG0 do{ asm volatile("s_waitcnt lgkmcnt(0)":::"memory"); \
                 __builtin_amdgcn_sched_barrier(0); }while(0)
#define WVM6 asm volatile("s_waitcnt vmcnt(6)":::"memory")

// ---------- k_frames: framesEO [32][1024][ evens(512) | odds(512) ] bf16 ----------
// + X[256] (self-paired bin) via 2 dot-reductions + zero-pad cols 513..575
__global__ void k_frames(const float* __restrict__ audio,
                         const float* __restrict__ basis,
                         unsigned short* __restrict__ frames,
                         unsigned short* __restrict__ magT){
  __shared__ float swr[4], swi[4];
  int tid = threadIdx.x;
  int gid = blockIdx.x * 256 + tid;
  int b   = gid >> 17;
  int rem = gid & 131071;
  int t   = rem >> 7;
  int k0  = (rem & 127) << 3;
  int s0  = t * 256 + k0 - PADL;
  const float* ap = audio + (long)b * T_AUDIO;
  float v[8];
  if (s0 >= 0 && s0 + 7 < T_AUDIO){
    f32x4 a0 = *(const f32x4*)(ap + s0);
    f32x4 a1 = *(const f32x4*)(ap + s0 + 4);
    v[0]=a0[0]; v[1]=a0[1]; v[2]=a0[2]; v[3]=a0[3];
    v[4]=a1[0]; v[5]=a1[1]; v[6]=a1[2]; v[7]=a1[3];
  } else {
    #pragma unroll
    for (int e = 0; e < 8; ++e){
      int s = s0 + e;
      if (s < 0) s = -s;
      if (s >= T_AUDIO) s = 2*(T_AUDIO-1) - s;
      v[e] = ap[s];
    }
  }
  bf16x4 ev, od;
  #pragma unroll
  for (int e = 0; e < 4; ++e){
    ev[e] = (short)f2bf(v[2*e]);
    od[e] = (short)f2bf(v[2*e+1]);
  }
  long fb = ((long)b << 20) + t * 1024;
  *(bf16x4*)(frames + fb + (k0 >> 1))       = ev;
  *(bf16x4*)(frames + fb + 512 + (k0 >> 1)) = od;

  // X[256]: real row = basis[256], imag row = basis[769]
  const float* r256 = basis + 256 * 1024 + k0;
  const float* i256 = basis + 769 * 1024 + k0;
  float dr = 0.f, di = 0.f;
  #pragma unroll
  for (int e = 0; e < 8; ++e){ dr += v[e]*r256[e]; di += v[e]*i256[e]; }
  #pragma unroll
  for (int off = 32; off; off >>= 1){
    dr += __shfl_down(dr, off, 64);
    di += __shfl_down(di, off, 64);
  }
  int lane = tid & 63, wid = tid >> 6;
  if (lane == 0){ swr[wid] = dr; swi[wid] = di; }
  __syncthreads();
  long tg = (long)b * 1024 + t;
  if (tid == 0 || tid == 128){
    float R = (tid == 0) ? (swr[0] + swr[1]) : (swr[2] + swr[3]);
    float I = (tid == 0) ? (swi[0] + swi[1]) : (swi[2] + swi[3]);
    magT[tg * CPAD + 256] = f2bf(sqrtf(R*R + I*I));
  }
  int c = tid & 127;
  if (c < 63) magT[tg * CPAD + 513 + c] = 0;
}

// ---------- k_basis3: bi2 [1024][512] bf16 ----------
// rows 0..511  = E: row R -> c=R>>1, part=R&1, samples n=2m   (src basis[c+513*part])
// rows 512..   = O: same with n=2m+1
__global__ void k_basis3(const float* __restrict__ basis, unsigned short* __restrict__ bi2){
  int gid = blockIdx.x * 256 + threadIdx.x;   // 1024 * 64
  int R  = gid >> 6;
  int m0 = (gid & 63) << 3;
  int half = R >> 9, Rl = R & 511;
  int srcr = (Rl >> 1) + 513 * (Rl & 1);
  const float* sp = basis + srcr * 1024 + 2 * m0 + half;
  bf16x8 o;
  #pragma unroll
  for (int e = 0; e < 8; ++e) o[e] = (short)f2bf(sp[2*e]);
  *(bf16x8*)(bi2 + R * 512 + m0) = o;
}

// ---------- k_w: mel weights [80][576] bf16, zero-padded ----------
__global__ void k_w(const float* __restrict__ w, unsigned short* __restrict__ wb){
  int gid = blockIdx.x * 256 + threadIdx.x;
  if (gid >= NMELS * CPAD) return;
  int m = gid / CPAD, c = gid % CPAD;
  float v = (c < CUTOFF) ? w[m * CUTOFF + c] : 0.f;
  wb[gid] = f2bf(v);
}

// ---------- k_stft: E/O-split GEMM  M=1024(256/block) N=32768(256) K=512, BK=32 ----------
// per buffer d (48KB, ring of 3): A-E [0,8K) 128r x 64B | A-O [8K,16K) | B-even [16K,32K) 256r | B-odd [32K,48K)
// chunk swizzle: lds[row][ch] = glob[row][ch ^ ((row>>1)&3)]
__launch_bounds__(512, 2)
__global__ void k_stft(const unsigned short* __restrict__ bi2,
                       const unsigned short* __restrict__ frames,
                       unsigned short* __restrict__ magT){
  __shared__ __align__(16) char LDS[147456];
  const int tid = threadIdx.x;
  const int l   = tid & 63, w = tid >> 6;
  const int wm  = w >> 2, wn = w & 3;

  int bx = blockIdx.x;
  int sw = ((bx & 7) << 6) | (bx >> 3);       // XCD swizzle (512 % 8 == 0, bijective)
  const int g  = sw & 3;                      // c-group: cs [g*64, g*64+64)
  const int n0 = (sw >> 2) << 8;

  // ---- stage side: dest linear (tid*16), source pre-swizzled ----
  const int srow = tid >> 2;
  const int cs16 = (((tid & 3) ^ ((tid >> 3) & 3)) << 4);
  const char* AgE = (const char*)bi2 + (long)(g * 128 + srow) * 1024 + cs16;
  const char* AgO = AgE + 524288;                                   // +512 rows
  const char* Bg0 = (const char*)frames + (long)(n0 + srow) * 2048 + cs16;
  const char* Bg1 = Bg0 + 262144;                                   // +128 rows
  // kb = k-tile byte offset (s*64); odd half at +1024
  #define STG(d_, kb_) do{ \
    char* L_ = LDS + (d_)*49152 + tid*16; \
    gload_lds16(AgE + (kb_), L_); \
    gload_lds16(AgO + (kb_), L_ + 8192); \
    gload_lds16(Bg0 + (kb_), L_ + 16384); }while(0)
  #define STG2(d_, kb_) do{ \
    char* L_ = LDS + (d_)*49152 + tid*16; \
    gload_lds16(Bg1 + (kb_),        L_ + 24576); \
    gload_lds16(Bg0 + (kb_) + 1024, L_ + 32768); \
    gload_lds16(Bg1 + (kb_) + 1024, L_ + 40960); }while(0)

  // ---- read side ----
  const int x  = l & 15;
  const int ch = (((l >> 4) ^ ((x >> 1) & 3)) << 4);
  const char* Ab0 = LDS +          wm * 4096 + x * 64 + ch;           // A-E base, d=0
  const char* Bb0 = LDS + 16384 + wn * 4096 + x * 64 + ch;           // B-even base, d=0

  f32x4 accE[4][4] = {}, accO[4][4] = {};
  bf16x8 af[4], bq[4];

  #define RD(base, off) do{ _Pragma("unroll") \
    for (int i_ = 0; i_ < 4; ++i_) af[i_] = *(const bf16x8*)((base) + (off) + i_*1024); \
    _Pragma("unroll") \
    for (int j_ = 0; j_ < 4; ++j_) bq[j_] = *(const bf16x8*)((base) + (off) + 16384 - (0) + 0 + j_*0); }while(0)
  // (RD unused; explicit reads below for clarity)

  #define MME(ACC) do{ __builtin_amdgcn_s_setprio(1); _Pragma("unroll") \
    for (int i_ = 0; i_ < 4; ++i_){ _Pragma("unroll") \
      for (int j_ = 0; j_ < 4; ++j_) \
        ACC[i_][j_] = __builtin_amdgcn_mfma_f32_16x16x32_bf16(af[i_], bq[j_], ACC[i_][j_], 0, 0, 0); } \
    __builtin_amdgcn_s_setprio(0); }while(0)

  // ---- prologue: stage step0 -> buf0, step1 -> buf1 ----
  STG(0, 0); STG2(0, 0);
  STG(1, 64); STG2(1, 64);
  WVM6;
  BAR;

  #pragma unroll
  for (int s = 0; s < 16; ++s){
    const int d  = s % 3;
    const int td = (s + 2) % 3;
    const int kb = ((s + 2) & 15) * 64;
    const char* Ab = Ab0 + d * 49152;
    const char* Bb = Bb0 + d * 49152;

    // ph1: E frags (A-E + B-even), stage first half of step s+2
    #pragma unroll
    for (int i_ = 0; i_ < 4; ++i_) af[i_] = *(const bf16x8*)(Ab + i_*1024);
    #pragma unroll
    for (int j_ = 0; j_ < 4; ++j_) bq[j_] = *(const bf16x8*)(Bb + j_*1024);
    STG(td, kb);
    BAR; WLG0;
    MME(accE);
    BAR;

    // ph2: O frags (A-O + B-odd), stage second half; counted vmcnt
    #pragma unroll
    for (int i_ = 0; i_ < 4; ++i_) af[i_] = *(const bf16x8*)(Ab + 8192 + i_*1024);
    #pragma unroll
    for (int j_ = 0; j_ < 4; ++j_) bq[j_] = *(const bf16x8*)(Bb + 16384 + j_*1024);
    STG2(td, kb);
    WVM6;
    BAR; WLG0;
    MME(accO);
    BAR;
  }

  // ---- epilogue: X[c]=E+O, X[512-c]=conj(E)-conj(O) -> |.| ----
  const long tbase = (long)(n0 + wn * 64 + x);
  const int  q4 = (l >> 4) << 2;
  #pragma unroll
  for (int i = 0; i < 4; ++i){
    int mrow = wm * 64 + i * 16 + q4;       // multiple of 4
    int c0 = g * 64 + (mrow >> 1);          // even, 0..254
    #pragma unroll
    for (int j = 0; j < 4; ++j){
      long t = tbase + j * 16;
      f32x4 E = accE[i][j], O = accO[i][j];
      float m1 = sqrtf((E[0]+O[0])*(E[0]+O[0]) + (E[1]+O[1])*(E[1]+O[1]));  // X[c0]
      float m2 = sqrtf((E[2]+O[2])*(E[2]+O[2]) + (E[3]+O[3])*(E[3]+O[3]));  // X[c0+1]
      float m3 = sqrtf((E[0]-O[0])*(E[0]-O[0]) + (E[1]-O[1])*(E[1]-O[1]));  // X[512-c0]
      float m4 = sqrtf((E[2]-O[2])*(E[2]-O[2]) + (E[3]-O[3])*(E[3]-O[3]));  // X[511-c0]
      unsigned pack = (unsigned)f2bf(m1) | ((unsigned)f2bf(m2) << 16);
      *(unsigned*)(magT + t * CPAD + c0) = pack;
      magT[t * CPAD + 512 - c0] = f2bf(m3);
      magT[t * CPAD + 511 - c0] = f2bf(m4);
    }
  }
  #undef STG
  #undef STG2
  #undef RD
  #undef MME
}

// ---------- k_mel: [80][576] x [576][t] + log(clip) -> out [32][80][1024] f32 ----------
__launch_bounds__(256)
__global__ void k_mel(const unsigned short* __restrict__ wb,
                      const unsigned short* __restrict__ magT,
                      float* __restrict__ out){
  __shared__ unsigned short Ws[80 * 32];
  __shared__ unsigned short Ms[128 * 32];
  int tid  = threadIdx.x, lane = tid & 63, wid = tid >> 6;
  int bx   = blockIdx.x;
  int bt   = bx & 7, b = bx >> 3;
  int t0   = bt * 128;
  f32x4 acc[5][2] = {};
  const char* Mb = (const char*)(magT + ((long)b * 1024 + t0) * CPAD);
  const char* Wb = (const char*)wb;

  for (int kt = 0; kt < 18; ++kt){
    int k0b = kt * 64;
    {
      int o = tid * 16;
      gload_lds16(Wb + (o >> 6) * 1152 + k0b + (o & 63), (char*)Ws + wid * 1024);
      if (wid == 0){
        int o2 = 4096 + lane * 16;
        gload_lds16(Wb + (o2 >> 6) * 1152 + k0b + (o2 & 63), (char*)Ws + 4096);
      }
    }
    #pragma unroll
    for (int q = 0; q < 2; ++q){
      int o = (q * 256 + tid) * 16;
      gload_lds16(Mb + (long)(o >> 6) * 1152 + k0b + (o & 63), (char*)Ms + q * 4096 + wid * 1024);
    }
    __syncthreads();
    bf16x8 af[5], bfr[2];
    int kb = (lane >> 4) << 4;
    #pragma unroll
    for (int i = 0; i < 5; ++i)
      af[i] = *(const bf16x8*)((const char*)Ws + (i*16 + (lane & 15)) * 64 + kb);
    #pragma unroll
    for (int j = 0; j < 2; ++j)
      bfr[j] = *(const bf16x8*)((const char*)Ms + (wid*32 + j*16 + (lane & 15)) * 64 + kb);
    #pragma unroll
    for (int i = 0; i < 5; ++i)
      #pragma unroll
      for (int j = 0; j < 2; ++j)
        acc[i][j] = __builtin_amdgcn_mfma_f32_16x16x32_bf16(af[i], bfr[j], acc[i][j], 0, 0, 0);
    __syncthreads();
  }
  #pragma unroll
  for (int i = 0; i < 5; ++i)
    #pragma unroll
    for (int j = 0; j < 2; ++j){
      int m = i*16 + ((lane >> 4) << 2);
      int t = t0 + wid*32 + j*16 + (lane & 15);
      #pragma unroll
      for (int r = 0; r < 4; ++r){
        float v = acc[i][j][r];
        out[((long)b * NMELS + (m + r)) * 1024 + t] = logf(fmaxf(v, 1e-5f));
      }
    }
}

__global__ void k_sentinel(float* out, int n){
  int i = blockIdx.x * 256 + threadIdx.x;
  if (i < n) out[i] = 12345.0f;
}

extern "C" void kernel_launch(void* const* d_in, const int* in_sizes, int n_in,
                              void* d_out, int out_size, void* d_ws, size_t ws_size,
                              hipStream_t stream){
  const float* audio = (const float*)d_in[0];
  const float* basis = (const float*)d_in[1];
  const float* melw  = (const float*)d_in[2];
  float* out = (float*)d_out;

  size_t off_frames = 0;
  size_t off_bi     = off_frames + (size_t)32 * 1024 * 1024 * 2;   // 67,108,864
  size_t off_wb     = off_bi     + (size_t)1024 * 1024 * 2;        // slot 2 MB (bi2 uses 1 MB)
  size_t off_mag    = off_wb     + (size_t)NMELS * CPAD * 2;
  size_t total      = off_mag    + (size_t)32 * 1024 * CPAD * 2;   // = 107,046,912

  if (ws_size < total){
    k_sentinel<<<(out_size + 255) / 256, 256, 0, stream>>>(out, out_size);
    return;
  }
  char* ws = (char*)d_ws;
  unsigned short* frames = (unsigned short*)(ws + off_frames);
  unsigned short* bi2    = (unsigned short*)(ws + off_bi);
  unsigned short* wb     = (unsigned short*)(ws + off_wb);
  unsigned short* magT   = (unsigned short*)(ws + off_mag);

  k_frames<<<16384, 256, 0, stream>>>(audio, basis, frames, magT);
  k_basis3<<<  256, 256, 0, stream>>>(basis, bi2);
  k_w     <<<  180, 256, 0, stream>>>(melw, wb);
  k_stft  <<<  512, 512, 0, stream>>>(bi2, frames, magT);
  k_mel   <<<  256, 256, 0, stream>>>(wb, magT, out);
}